// Round 3
// baseline (333.652 us; speedup 1.0000x reference)
//
#include <hip/hip_runtime.h>

#define BATCH  2
#define DM     96
#define DI     192
#define NSTATE 16
#define RRANK  6
#define KDIR   6
#define L      4096
#define ROWW   40   // x_dbl row: [0..5]=dts, [6..7]=pad, [8..23]=B, [24..39]=C
#define LC     32
#define NCHUNK (L / LC)   // 128
#define HALO   64

__device__ __forceinline__ int map_s(int k, int l) {
  int lp = (k & 1) ? (L - 1 - l) : l;
  int kb = k >> 1;
  if (kb == 0) return lp;
  int a = lp >> 8, b = (lp >> 4) & 15, c = lp & 15;
  if (kb == 1) return (b << 8) | (a << 4) | c;
  return (b << 8) | (c << 4) | a;
}

__device__ __forceinline__ float dot4(float4 a, float4 b, float acc) {
  acc = fmaf(a.x, b.x, acc); acc = fmaf(a.y, b.y, acc);
  acc = fmaf(a.z, b.z, acc); acc = fmaf(a.w, b.w, acc);
  return acc;
}

// ---------------- weight pre-transpose (wave-uniform s_load layouts) --------
// wiT[q][oc][e]  = W_in[oc][4q+e]        q<24, oc<384   (36864)
// wpT[k][q][dd][e] = x_proj_w[k][dd][4q+e] q<48, dd<40  (46080, dd>=38 -> 0)
// woT[q][oc][e]  = W_out[oc][4q+e]        q<48, oc<96   (18432)
__global__ __launch_bounds__(256) void k_wt(const float* __restrict__ W_in,
    const float* __restrict__ xpw, const float* __restrict__ W_out,
    float* __restrict__ wiT, float* __restrict__ wpT, float* __restrict__ woT) {
  int i = blockIdx.x * 256 + threadIdx.x;
  if (i < 36864) {
    int q = i / 1536, rem = i - q * 1536, oc = rem >> 2, e = rem & 3;
    wiT[i] = W_in[oc * DM + q * 4 + e];
  } else if (i < 36864 + 46080) {
    int j = i - 36864;
    int k = j / 7680, r = j - k * 7680, q = r / 160, r2 = r - q * 160;
    int dd = r2 >> 2, e = r2 & 3;
    wpT[j] = (dd < 38) ? xpw[(k * 38 + dd) * DI + q * 4 + e] : 0.f;
  } else if (i < 36864 + 46080 + 18432) {
    int j = i - 36864 - 46080;
    int q = j / 384, r = j - q * 384, oc = r >> 2, e = r & 3;
    woT[j] = W_out[oc * DI + q * 4 + e];
  }
}

// ---------------- xz = x @ W_in^T ------------------------------------------
// block: 64 positions (lanes) x 48 oc (4 waves x 12). Weights via s_load.
__global__ __launch_bounds__(256) void k_xz(const float* __restrict__ x,
    const float* __restrict__ wiT, float* __restrict__ xe_c, float* __restrict__ z) {
  int blk = blockIdx.x;
  int slice = blk & 7, tile = (blk >> 3) & 63, b = blk >> 9;
  int w = __builtin_amdgcn_readfirstlane(threadIdx.x >> 6);
  int lane = threadIdx.x & 63;
  int oc0 = slice * 48 + w * 12;
  int s = (tile << 6) + lane;
  const float4* xg = (const float4*)(x + ((size_t)(b * L + s)) * DM);
  float acc[12];
  #pragma unroll
  for (int m = 0; m < 12; ++m) acc[m] = 0.f;
  #pragma unroll
  for (int pass = 0; pass < 2; ++pass) {
    float4 xr[12];
    #pragma unroll
    for (int j = 0; j < 12; ++j) xr[j] = xg[pass * 12 + j];
    #pragma unroll
    for (int qq = 0; qq < 12; ++qq) {
      int q = pass * 12 + qq;
      const float4* wv = (const float4*)(wiT + ((size_t)q * 384 + oc0) * 4);
      #pragma unroll
      for (int m = 0; m < 12; ++m) acc[m] = dot4(xr[qq], wv[m], acc[m]);
    }
  }
  if (oc0 < DI) {
    #pragma unroll
    for (int m = 0; m < 12; ++m)
      xe_c[((size_t)(b * DI + oc0 + m)) * L + s] = acc[m];
  } else {
    #pragma unroll
    for (int m = 0; m < 12; ++m)
      z[((size_t)(b * L + s)) * DI + (oc0 - DI + m)] = acc[m];
  }
}

// ---------------- depthwise conv3d + SiLU -> xc_t[b][s][c] ------------------
// padded LDS volume (no guards), register sliding window along d.
#define CPITCH 19
#define CPLANE 342            // 18*19
#define CVOL   6156           // 18*342
__global__ __launch_bounds__(256) void k_conv(const float* __restrict__ xe_c,
    const float* __restrict__ conv_w, const float* __restrict__ conv_b,
    float* __restrict__ xc_t) {
  __shared__ float chp[CVOL];
  int b = blockIdx.x / DI, c = blockIdx.x % DI;
  for (int i = threadIdx.x; i < CVOL; i += 256) chp[i] = 0.f;
  __syncthreads();
  const float4* src = (const float4*)(xe_c + ((size_t)(b * DI + c)) * L);
  for (int i = threadIdx.x; i < L / 4; i += 256) {
    float4 v = src[i];
    int s = i * 4;
    int d = s >> 8, h = (s >> 4) & 15, w0 = s & 15;
    int base = (d + 1) * CPLANE + (h + 1) * CPITCH + (w0 + 1);
    chp[base] = v.x; chp[base + 1] = v.y; chp[base + 2] = v.z; chp[base + 3] = v.w;
  }
  float wreg[27];
  #pragma unroll
  for (int j = 0; j < 27; ++j) wreg[j] = conv_w[c * 27 + j];
  float bias = conv_b[c];
  __syncthreads();
  int t = threadIdx.x;
  int d0 = (t >> 6) << 2, h = (t >> 2) & 15, wq = (t & 3) << 2;
  float win[3][18];   // [plane slot][3 rows x 6 w]
  #pragma unroll
  for (int pi = 0; pi < 2; ++pi) {
    int dd = d0 - 1 + pi;
    int base = (dd + 1) * CPLANE + h * CPITCH + wq;
    #pragma unroll
    for (int r = 0; r < 3; ++r)
      #pragma unroll
      for (int j = 0; j < 6; ++j)
        win[pi][r * 6 + j] = chp[base + r * CPITCH + j];
  }
  float* dst = xc_t + (size_t)b * L * DI + c;
  #pragma unroll
  for (int dstep = 0; dstep < 4; ++dstep) {
    int d = d0 + dstep;
    {   // load plane d+1 into slot (dstep+2)%3
      int base = (d + 2) * CPLANE + h * CPITCH + wq;
      float* wp = win[(dstep + 2) % 3];
      #pragma unroll
      for (int r = 0; r < 3; ++r)
        #pragma unroll
        for (int j = 0; j < 6; ++j)
          wp[r * 6 + j] = chp[base + r * CPITCH + j];
    }
    #pragma unroll
    for (int j = 0; j < 4; ++j) {
      float acc = bias;
      #pragma unroll
      for (int kd = 0; kd < 3; ++kd) {
        const float* pw = win[(dstep + kd) % 3];
        #pragma unroll
        for (int kh = 0; kh < 3; ++kh)
          #pragma unroll
          for (int kw = 0; kw < 3; ++kw)
            acc = fmaf(pw[kh * 6 + j + kw], wreg[kd * 9 + kh * 3 + kw], acc);
      }
      float sv = acc / (1.f + __expf(-acc));
      int s = (d << 8) | (h << 4) | (wq + j);
      dst[(size_t)s * DI] = sv;
    }
  }
}

// ---------------- x_dbl rows: lanes own l, waves own dd-decades -------------
__global__ __launch_bounds__(256) void k_proj(const float* __restrict__ xc_t,
    const float* __restrict__ wpT, float* __restrict__ xdbl) {
  int blk = blockIdx.x;
  int tile = blk & 63, bk = blk >> 6;
  int k = bk % KDIR, b = bk / KDIR;
  int w = __builtin_amdgcn_readfirstlane(threadIdx.x >> 6);
  int lane = threadIdx.x & 63;
  int dd0 = w * 10;
  int l = (tile << 6) + lane;
  int s = map_s(k, l);
  const float4* xg = (const float4*)(xc_t + ((size_t)(b * L + s)) * DI);
  float acc[10];
  #pragma unroll
  for (int m = 0; m < 10; ++m) acc[m] = 0.f;
  #pragma unroll
  for (int pass = 0; pass < 3; ++pass) {
    float4 xr[16];
    #pragma unroll
    for (int j = 0; j < 16; ++j) xr[j] = xg[pass * 16 + j];
    #pragma unroll
    for (int qq = 0; qq < 16; ++qq) {
      int q = pass * 16 + qq;
      const float4* wv = (const float4*)(wpT + ((size_t)(k * 48 + q) * 40 + dd0) * 4);
      #pragma unroll
      for (int m = 0; m < 10; ++m) acc[m] = dot4(xr[qq], wv[m], acc[m]);
    }
  }
  float* orow = xdbl + ((size_t)bk * L + l) * ROWW;
  #pragma unroll
  for (int m = 0; m < 10; ++m) {
    int dd = dd0 + m;
    if (dd < 38) orow[dd < 6 ? dd : dd + 2] = acc[m];
  }
}

// ---------------- chunked selective scan (scalar row loads, no LDS) ---------
__global__ void __launch_bounds__(192, 5) k_scan(const float* __restrict__ xc_t,
    const float* __restrict__ xdbl, const float* __restrict__ dtw,
    const float* __restrict__ dtb, const float* __restrict__ A_logs,
    const float* __restrict__ Ds, float* __restrict__ y_sum) {
  int blk = blockIdx.x;
  int chk = blk & (NCHUNK - 1);
  int bk = blk >> 7;
  int k = bk % KDIR, b = bk / KDIR;
  int c = threadIdx.x;
  float wdt[RRANK];
  #pragma unroll
  for (int r = 0; r < RRANK; ++r) wdt[r] = dtw[(k * DI + c) * RRANK + r];
  float bias = dtb[k * DI + c];
  float Dv = Ds[k * DI + c];
  const float* alog = A_logs + (size_t)(k * DI + c) * NSTATE;
  bool fast = true;
  #pragma unroll
  for (int n = 0; n < NSTATE; ++n)
    fast = fast && (fabsf(__expf(alog[n]) - (float)(n + 1)) < 1e-4f);
  float h[NSTATE];
  #pragma unroll
  for (int n = 0; n < NSTATE; ++n) h[n] = 0.f;
  int lo = chk * LC;
  int ls = lo - HALO; if (ls < 0) ls = 0;
  const float* __restrict__ rb = xdbl + (size_t)bk * L * ROWW;
  const float* ub = xc_t + (size_t)b * L * DI + c;
  float* yb = y_sum + (size_t)b * L * DI + c;

  int s_cur = map_s(k, ls);
  float u_cur = ub[(size_t)s_cur * DI];
  if (fast) {
    for (int l = ls; l < lo + LC; ++l) {
      float u_nxt = u_cur; int s_nxt = s_cur;
      if (l + 1 < lo + LC) { s_nxt = map_s(k, l + 1); u_nxt = ub[(size_t)s_nxt * DI]; }
      const float* row = rb + (size_t)l * ROWW;   // wave-uniform -> s_load
      float r0 = row[0], r1 = row[1], r2 = row[2], r3 = row[3], r4 = row[4], r5 = row[5];
      float Bv[16], Cv[16];
      #pragma unroll
      for (int n = 0; n < NSTATE; ++n) Bv[n] = row[8 + n];
      #pragma unroll
      for (int n = 0; n < NSTATE; ++n) Cv[n] = row[24 + n];
      float dtv = bias;
      dtv = fmaf(r0, wdt[0], dtv); dtv = fmaf(r1, wdt[1], dtv);
      dtv = fmaf(r2, wdt[2], dtv); dtv = fmaf(r3, wdt[3], dtv);
      dtv = fmaf(r4, wdt[4], dtv); dtv = fmaf(r5, wdt[5], dtv);
      float sp = fmaxf(dtv, 0.f) + __logf(1.f + __expf(-fabsf(dtv)));
      float e1 = __expf(-sp);
      float dtu = sp * u_cur;
      float p2 = e1 * e1, p4 = p2 * p2, p8 = p4 * p4;
      float dA[NSTATE];
      dA[0] = e1; dA[1] = p2; dA[2] = p2 * e1; dA[3] = p4;
      dA[4] = p4 * e1; dA[5] = p4 * p2; dA[6] = dA[2] * p4; dA[7] = p8;
      #pragma unroll
      for (int n = 8; n < 16; ++n) dA[n] = dA[n - 8] * p8;
      float y = 0.f;
      #pragma unroll
      for (int n = 0; n < NSTATE; ++n) {
        h[n] = fmaf(dA[n], h[n], dtu * Bv[n]);
        y = fmaf(h[n], Cv[n], y);
      }
      if (l >= lo) atomicAdd(yb + (size_t)s_cur * DI, fmaf(Dv, u_cur, y));
      u_cur = u_nxt; s_cur = s_nxt;
    }
  } else {
    for (int l = ls; l < lo + LC; ++l) {
      const float* row = rb + (size_t)l * ROWW;
      float dtv = bias;
      #pragma unroll
      for (int r = 0; r < RRANK; ++r) dtv = fmaf(row[r], wdt[r], dtv);
      float sp = fmaxf(dtv, 0.f) + __logf(1.f + __expf(-fabsf(dtv)));
      int s = map_s(k, l);
      float u = ub[(size_t)s * DI];
      float dtu = sp * u;
      float y = 0.f;
      #pragma unroll
      for (int n = 0; n < NSTATE; ++n) {
        float dAv = __expf(sp * (-__expf(alog[n])));
        h[n] = fmaf(dAv, h[n], dtu * row[8 + n]);
        y = fmaf(h[n], row[24 + n], y);
      }
      if (l >= lo) atomicAdd(yb + (size_t)s * DI, fmaf(Dv, u, y));
    }
  }
}

// ---------------- LN -> gate -> W_out ---------------------------------------
#define FPITCH 196
__global__ __launch_bounds__(512) void k_final(const float* __restrict__ y_sum,
    const float* __restrict__ zb, const float* __restrict__ lnw,
    const float* __restrict__ lnb, const float* __restrict__ woT,
    float* __restrict__ out) {
  __shared__ float ysg[64 * FPITCH];
  int p0 = blockIdx.x << 6;
  int t = threadIdx.x;
  {
    int r = t >> 3, lg = t & 7;
    const float* yrow = y_sum + (size_t)(p0 + r) * DI;
    float v[24], s1 = 0.f, s2 = 0.f;
    #pragma unroll
    for (int j = 0; j < 24; ++j) {
      float vv = yrow[lg + 8 * j];
      v[j] = vv; s1 += vv; s2 += vv * vv;
    }
    s1 += __shfl_xor(s1, 1, 64); s2 += __shfl_xor(s2, 1, 64);
    s1 += __shfl_xor(s1, 2, 64); s2 += __shfl_xor(s2, 2, 64);
    s1 += __shfl_xor(s1, 4, 64); s2 += __shfl_xor(s2, 4, 64);
    float mu = s1 * (1.f / DI);
    float var = s2 * (1.f / DI) - mu * mu;
    float rs = rsqrtf(var + 1e-5f);
    const float* zrow = zb + (size_t)(p0 + r) * DI;
    #pragma unroll
    for (int j = 0; j < 24; ++j) {
      int cc = lg + 8 * j;
      float g = zrow[cc];
      float yl = (v[j] - mu) * rs * lnw[cc] + lnb[cc];
      ysg[r * FPITCH + cc] = yl * (g / (1.f + __expf(-g)));
    }
  }
  __syncthreads();
  int w = __builtin_amdgcn_readfirstlane(t >> 6);
  int lane = t & 63;
  int oc0 = w * 12;
  const float4* yr4 = (const float4*)(ysg + lane * FPITCH);
  float acc[12];
  #pragma unroll
  for (int m = 0; m < 12; ++m) acc[m] = 0.f;
  for (int q = 0; q < 48; ++q) {
    float4 yv = yr4[q];
    const float4* wv = (const float4*)(woT + ((size_t)q * 96 + oc0) * 4);
    #pragma unroll
    for (int m = 0; m < 12; ++m) acc[m] = dot4(yv, wv[m], acc[m]);
  }
  float* orow = out + (size_t)(p0 + lane) * DM + oc0;
  #pragma unroll
  for (int m = 0; m < 12; ++m) orow[m] = acc[m];
}

extern "C" void kernel_launch(void* const* d_in, const int* in_sizes, int n_in,
                              void* d_out, int out_size, void* d_ws, size_t ws_size,
                              hipStream_t stream) {
  const float* x        = (const float*)d_in[0];
  const float* W_in     = (const float*)d_in[1];
  const float* conv_w   = (const float*)d_in[2];
  const float* conv_b   = (const float*)d_in[3];
  const float* x_proj_w = (const float*)d_in[4];
  const float* dt_proj_w= (const float*)d_in[5];
  const float* dt_proj_b= (const float*)d_in[6];
  const float* A_logs   = (const float*)d_in[7];
  const float* Ds       = (const float*)d_in[8];
  const float* ln_w     = (const float*)d_in[9];
  const float* ln_b     = (const float*)d_in[10];
  const float* W_out    = (const float*)d_in[11];
  float* out = (float*)d_out;

  float* ws   = (float*)d_ws;
  float* xe_c = ws;                                     // B*DI*L
  float* zb   = xe_c + (size_t)BATCH * DI * L;          // B*L*DI
  float* xc_t = zb   + (size_t)BATCH * L * DI;          // B*L*DI
  float* xdbl = xc_t + (size_t)BATCH * L * DI;          // B*K*L*ROWW
  float* ysum = xdbl + (size_t)BATCH * KDIR * L * ROWW; // B*L*DI
  float* wiT  = ysum + (size_t)BATCH * L * DI;          // 36864
  float* wpT  = wiT + 36864;                            // 46080
  float* woT  = wpT + 46080;                            // 18432

  k_wt  <<<396, 256, 0, stream>>>(W_in, x_proj_w, W_out, wiT, wpT, woT);
  k_xz  <<<BATCH * 64 * 8, 256, 0, stream>>>(x, wiT, xe_c, zb);
  k_conv<<<BATCH * DI, 256, 0, stream>>>(xe_c, conv_w, conv_b, xc_t);
  hipMemsetAsync(ysum, 0, (size_t)BATCH * L * DI * sizeof(float), stream);
  k_proj<<<BATCH * KDIR * 64, 256, 0, stream>>>(xc_t, wpT, xdbl);
  k_scan<<<BATCH * KDIR * NCHUNK, DI, 0, stream>>>(xc_t, xdbl, dt_proj_w, dt_proj_b,
                                                   A_logs, Ds, ysum);
  k_final<<<BATCH * L / 64, 512, 0, stream>>>(ysum, zb, ln_w, ln_b, woT, out);
}

// Round 4
// 281.356 us; speedup vs baseline: 1.1859x; 1.1859x over previous
//
#include <hip/hip_runtime.h>

#define BATCH  2
#define DM     96
#define DI     192
#define NSTATE 16
#define RRANK  6
#define KDIR   6
#define L      4096
#define ROWW   40   // x_dbl row: [0..5]=dts, [6..7]=pad, [8..23]=B, [24..39]=C
#define LC     64
#define NCHUNK (L / LC)   // 64
#define HALO   64

__device__ __forceinline__ int map_s(int k, int l) {
  int lp = (k & 1) ? (L - 1 - l) : l;
  int kb = k >> 1;
  if (kb == 0) return lp;
  int a = lp >> 8, b = (lp >> 4) & 15, c = lp & 15;
  if (kb == 1) return (b << 8) | (a << 4) | c;
  return (b << 8) | (c << 4) | a;
}

__device__ __forceinline__ float dot4(float4 a, float4 b, float acc) {
  acc = fmaf(a.x, b.x, acc); acc = fmaf(a.y, b.y, acc);
  acc = fmaf(a.z, b.z, acc); acc = fmaf(a.w, b.w, acc);
  return acc;
}

// ---------------- weight pre-transpose --------------------------------------
// wiT[q][oc][e]   = W_in[oc][4q+e]          q<24, oc<384
// wpT[k][q][dd][e]= x_proj_w[k][dd][4q+e]   q<48, dd<40 (dd>=38 -> 0)
// woT[q][oc][e]   = W_out[oc][4q+e]         q<48, oc<96
__global__ __launch_bounds__(256) void k_wt(const float* __restrict__ W_in,
    const float* __restrict__ xpw, const float* __restrict__ W_out,
    float* __restrict__ wiT, float* __restrict__ wpT, float* __restrict__ woT) {
  int i = blockIdx.x * 256 + threadIdx.x;
  if (i < 36864) {
    int q = i / 1536, rem = i - q * 1536, oc = rem >> 2, e = rem & 3;
    wiT[i] = W_in[oc * DM + q * 4 + e];
  } else if (i < 36864 + 46080) {
    int j = i - 36864;
    int k = j / 7680, r = j - k * 7680, q = r / 160, r2 = r - q * 160;
    int dd = r2 >> 2, e = r2 & 3;
    wpT[j] = (dd < 38) ? xpw[(k * 38 + dd) * DI + q * 4 + e] : 0.f;
  } else if (i < 36864 + 46080 + 18432) {
    int j = i - 36864 - 46080;
    int q = j / 384, r = j - q * 384, oc = r >> 2, e = r & 3;
    woT[j] = W_out[oc * DI + q * 4 + e];
  }
}

// ---------------- xz = x @ W_in^T -------------------------------------------
// lanes own positions; weights via wave-uniform s_load; z routed through LDS
// transpose so stores stay coalesced.
__global__ __launch_bounds__(256) void k_xz(const float* __restrict__ x,
    const float* __restrict__ wiT, float* __restrict__ xe_c, float* __restrict__ z) {
  __shared__ float zt[64][49];
  int blk = blockIdx.x;
  int slice = blk & 7, tile = (blk >> 3) & 63, b = blk >> 9;
  int w = __builtin_amdgcn_readfirstlane(threadIdx.x >> 6);
  int lane = threadIdx.x & 63;
  int oc0 = slice * 48 + w * 12;
  int s = (tile << 6) + lane;
  const float4* xg = (const float4*)(x + ((size_t)(b * L + s)) * DM);
  float acc[12];
  #pragma unroll
  for (int m = 0; m < 12; ++m) acc[m] = 0.f;
  #pragma unroll
  for (int pass = 0; pass < 2; ++pass) {
    float4 xr[12];
    #pragma unroll
    for (int j = 0; j < 12; ++j) xr[j] = xg[pass * 12 + j];
    #pragma unroll
    for (int qq = 0; qq < 12; ++qq) {
      int q = pass * 12 + qq;
      const float4* wv = (const float4*)(wiT + ((size_t)q * 384 + oc0) * 4);
      #pragma unroll
      for (int m = 0; m < 12; ++m) acc[m] = dot4(xr[qq], wv[m], acc[m]);
    }
  }
  if (slice < 4) {          // xe half: channel-major, lanes=s -> coalesced
    #pragma unroll
    for (int m = 0; m < 12; ++m)
      xe_c[((size_t)(b * DI + oc0 + m)) * L + s] = acc[m];
  } else {                  // z half: LDS transpose -> coalesced [p][c] stores
    #pragma unroll
    for (int m = 0; m < 12; ++m) zt[lane][w * 12 + m] = acc[m];
    __syncthreads();
    int zc0 = (slice - 4) * 48;
    for (int i = threadIdx.x; i < 64 * 48; i += 256) {
      int r = i / 48, cc = i - r * 48;
      z[((size_t)(b * L + (tile << 6) + r)) * DI + zc0 + cc] = zt[r][cc];
    }
  }
}

// ---------------- depthwise conv3d + SiLU, channel-major out ----------------
__global__ __launch_bounds__(256) void k_conv(const float* __restrict__ xe_c,
    const float* __restrict__ conv_w, const float* __restrict__ conv_b,
    float* __restrict__ xc_c) {
  __shared__ float ch[L];
  int b = blockIdx.x / DI, c = blockIdx.x % DI;
  const float4* src = (const float4*)(xe_c + ((size_t)(b * DI + c)) * L);
  for (int i = threadIdx.x; i < L / 4; i += 256) ((float4*)ch)[i] = src[i];
  float w[27];
  #pragma unroll
  for (int j = 0; j < 27; ++j) w[j] = conv_w[c * 27 + j];
  float bias = conv_b[c];
  __syncthreads();
  float* dst = xc_c + ((size_t)(b * DI + c)) * L;
  for (int i = threadIdx.x; i < L; i += 256) {
    int d = i >> 8, h = (i >> 4) & 15, iw = i & 15;
    float acc = bias;
    #pragma unroll
    for (int kd = 0; kd < 3; ++kd) {
      int dd = d + kd - 1;
      #pragma unroll
      for (int kh = 0; kh < 3; ++kh) {
        int hh = h + kh - 1;
        #pragma unroll
        for (int kw = 0; kw < 3; ++kw) {
          int wwp = iw + kw - 1;
          if ((unsigned)dd < 16u && (unsigned)hh < 16u && (unsigned)wwp < 16u)
            acc = fmaf(ch[(dd << 8) | (hh << 4) | wwp], w[kd * 9 + kh * 3 + kw], acc);
        }
      }
    }
    dst[i] = acc / (1.f + __expf(-acc));
  }
}

// ---------------- transpose [b][c][s] -> [b][s][c] --------------------------
__global__ __launch_bounds__(256) void k_tr(const float* __restrict__ src,
                                            float* __restrict__ dst) {
  __shared__ float t[32][33];
  int blk = blockIdx.x;
  int st = blk & 127, ct = (blk >> 7) % 6, b = blk / (128 * 6);
  int s0 = st << 5, c0 = ct << 5;
  int i = threadIdx.x >> 5, j = threadIdx.x & 31;
  #pragma unroll
  for (int k2 = 0; k2 < 4; ++k2)
    t[i + 8 * k2][j] = src[((size_t)(b * DI + c0 + i + 8 * k2)) * L + s0 + j];
  __syncthreads();
  #pragma unroll
  for (int k2 = 0; k2 < 4; ++k2)
    dst[((size_t)(b * L + s0 + i + 8 * k2)) * DI + c0 + j] = t[j][i + 8 * k2];
}

// ---------------- x_dbl = x_proj_w[k] @ xs rows -----------------------------
// coalesced staging into [q][lane] LDS (conflict-free b128 column reads),
// s_load weights, LDS-transposed coalesced stores.
__global__ __launch_bounds__(256) void k_proj(const float* __restrict__ xc_t,
    const float* __restrict__ wpT, float* __restrict__ xdbl) {
  __shared__ float4 xr[48 * 65];
  __shared__ float  xd[64][41];
  int blk = blockIdx.x;
  int tile = blk & 63, bk = blk >> 6;
  int k = bk % KDIR, b = bk / KDIR;
  int l0 = tile << 6;
  const float4* xsrc = (const float4*)xc_t;
  for (int i = threadIdx.x; i < 64 * 48; i += 256) {
    int p = i / 48, q = i - p * 48;
    int sidx = map_s(k, l0 + p);
    xr[q * 65 + p] = xsrc[((size_t)(b * L + sidx)) * 48 + q];
  }
  int w = __builtin_amdgcn_readfirstlane(threadIdx.x >> 6);
  int lane = threadIdx.x & 63;
  int dd0 = w * 10;
  __syncthreads();
  float acc[10];
  #pragma unroll
  for (int m = 0; m < 10; ++m) acc[m] = 0.f;
  for (int q = 0; q < 48; ++q) {
    float4 xv = xr[q * 65 + lane];
    const float4* wv = (const float4*)(wpT + ((size_t)(k * 48 + q) * 40 + dd0) * 4);
    #pragma unroll
    for (int m = 0; m < 10; ++m) acc[m] = dot4(xv, wv[m], acc[m]);
  }
  if (w == 0) { xd[lane][6] = 0.f; xd[lane][7] = 0.f; }
  #pragma unroll
  for (int m = 0; m < 10; ++m) {
    int dd = dd0 + m;
    if (dd < 38) xd[lane][dd < 6 ? dd : dd + 2] = acc[m];
  }
  __syncthreads();
  float* orow = xdbl + (size_t)bk * L * ROWW + (size_t)l0 * ROWW;
  for (int i = threadIdx.x; i < 64 * ROWW; i += 256) {
    int r = i / ROWW, cc = i - r * ROWW;
    orow[i] = xd[r][cc];
  }
}

// ---------------- chunked selective scan (LDS rows + SW pipeline) -----------
__global__ void __launch_bounds__(DI) k_scan(const float* __restrict__ xc_t,
    const float* __restrict__ xdbl, const float* __restrict__ dtw,
    const float* __restrict__ dtb, const float* __restrict__ A_logs,
    const float* __restrict__ Ds, float* __restrict__ y_sum) {
  __shared__ float4 rows[128 * 10];
  int blk = blockIdx.x;
  int chk = blk & (NCHUNK - 1);
  int bk = blk >> 6;
  int k = bk % KDIR, b = bk / KDIR;
  int c = threadIdx.x;
  int lo = chk * LC;
  int ls = lo - HALO; if (ls < 0) ls = 0;
  int lend = lo + LC;
  int nr = lend - ls;
  const float4* rsrc = (const float4*)(xdbl + (size_t)bk * L * ROWW) + (size_t)ls * 10;
  for (int i = c; i < nr * 10; i += DI) rows[i] = rsrc[i];
  float wdt[RRANK];
  #pragma unroll
  for (int r = 0; r < RRANK; ++r) wdt[r] = dtw[(k * DI + c) * RRANK + r];
  float bias = dtb[k * DI + c];
  float Dv = Ds[k * DI + c];
  const float* alog = A_logs + (size_t)(k * DI + c) * NSTATE;
  bool fast = true;
  #pragma unroll
  for (int n = 0; n < NSTATE; ++n)
    fast = fast && (fabsf(__expf(alog[n]) - (float)(n + 1)) < 1e-4f);
  float h[NSTATE];
  #pragma unroll
  for (int n = 0; n < NSTATE; ++n) h[n] = 0.f;
  const float* ub = xc_t + (size_t)b * L * DI + c;
  float* yb = y_sum + (size_t)b * L * DI + c;
  __syncthreads();

  if (fast) {  // A[n] == -(n+1): dA[n] = e1^(n+1)
    int s_cur = map_s(k, ls);
    float u_cur = ub[(size_t)s_cur * DI];
    float4 d0 = rows[0], d1 = rows[1];
    float4 B0 = rows[2], B1 = rows[3], B2 = rows[4], B3 = rows[5];
    for (int l = ls; l < lend; ++l) {
      int idx = l - ls;
      // current-iter C loads issued early
      float4 C0 = rows[idx * 10 + 6], C1 = rows[idx * 10 + 7];
      float4 C2 = rows[idx * 10 + 8], C3 = rows[idx * 10 + 9];
      // prefetch next-iter dts/B + u
      float4 nd0 = d0, nd1 = d1, nB0 = B0, nB1 = B1, nB2 = B2, nB3 = B3;
      float u_nxt = u_cur; int s_nxt = s_cur;
      if (l + 1 < lend) {
        int j = (idx + 1) * 10;
        nd0 = rows[j]; nd1 = rows[j + 1];
        nB0 = rows[j + 2]; nB1 = rows[j + 3]; nB2 = rows[j + 4]; nB3 = rows[j + 5];
        s_nxt = map_s(k, l + 1); u_nxt = ub[(size_t)s_nxt * DI];
      }
      float dtv = bias;
      dtv = fmaf(d0.x, wdt[0], dtv); dtv = fmaf(d0.y, wdt[1], dtv);
      dtv = fmaf(d0.z, wdt[2], dtv); dtv = fmaf(d0.w, wdt[3], dtv);
      dtv = fmaf(d1.x, wdt[4], dtv); dtv = fmaf(d1.y, wdt[5], dtv);
      float sp = fmaxf(dtv, 0.f) + __logf(1.f + __expf(-fabsf(dtv)));
      float e1 = __expf(-sp);
      float dtu = sp * u_cur;
      float p2 = e1 * e1, p4 = p2 * p2, p8 = p4 * p4;
      float dA1 = e1,       dA2 = p2,       dA3 = p2 * e1,  dA4 = p4;
      float dA5 = p4 * e1,  dA6 = p4 * p2,  dA7 = dA3 * p4, dA8 = p8;
      float y = 0.f;
      h[0]  = fmaf(dA1, h[0],  dtu * B0.x); y = fmaf(h[0],  C0.x, y);
      h[1]  = fmaf(dA2, h[1],  dtu * B0.y); y = fmaf(h[1],  C0.y, y);
      h[2]  = fmaf(dA3, h[2],  dtu * B0.z); y = fmaf(h[2],  C0.z, y);
      h[3]  = fmaf(dA4, h[3],  dtu * B0.w); y = fmaf(h[3],  C0.w, y);
      h[4]  = fmaf(dA5, h[4],  dtu * B1.x); y = fmaf(h[4],  C1.x, y);
      h[5]  = fmaf(dA6, h[5],  dtu * B1.y); y = fmaf(h[5],  C1.y, y);
      h[6]  = fmaf(dA7, h[6],  dtu * B1.z); y = fmaf(h[6],  C1.z, y);
      h[7]  = fmaf(dA8, h[7],  dtu * B1.w); y = fmaf(h[7],  C1.w, y);
      h[8]  = fmaf(dA8 * e1,  h[8],  dtu * B2.x); y = fmaf(h[8],  C2.x, y);
      h[9]  = fmaf(dA8 * p2,  h[9],  dtu * B2.y); y = fmaf(h[9],  C2.y, y);
      h[10] = fmaf(dA8 * dA3, h[10], dtu * B2.z); y = fmaf(h[10], C2.z, y);
      h[11] = fmaf(dA8 * p4,  h[11], dtu * B2.w); y = fmaf(h[11], C2.w, y);
      h[12] = fmaf(dA8 * dA5, h[12], dtu * B3.x); y = fmaf(h[12], C3.x, y);
      h[13] = fmaf(dA8 * dA6, h[13], dtu * B3.y); y = fmaf(h[13], C3.y, y);
      h[14] = fmaf(dA8 * dA7, h[14], dtu * B3.z); y = fmaf(h[14], C3.z, y);
      h[15] = fmaf(dA8 * dA8, h[15], dtu * B3.w); y = fmaf(h[15], C3.w, y);
      if (l >= lo) atomicAdd(yb + (size_t)s_cur * DI, fmaf(Dv, u_cur, y));
      d0 = nd0; d1 = nd1; B0 = nB0; B1 = nB1; B2 = nB2; B3 = nB3;
      u_cur = u_nxt; s_cur = s_nxt;
    }
  } else {     // generic fallback
    for (int l = ls; l < lend; ++l) {
      const float* rf = (const float*)&rows[(l - ls) * 10];
      float dtv = bias;
      #pragma unroll
      for (int r = 0; r < RRANK; ++r) dtv = fmaf(rf[r], wdt[r], dtv);
      float sp = fmaxf(dtv, 0.f) + __logf(1.f + __expf(-fabsf(dtv)));
      int s = map_s(k, l);
      float u = ub[(size_t)s * DI];
      float dtu = sp * u;
      float y = 0.f;
      #pragma unroll
      for (int n = 0; n < NSTATE; ++n) {
        float dAv = __expf(sp * (-__expf(alog[n])));
        h[n] = fmaf(dAv, h[n], dtu * rf[8 + n]);
        y = fmaf(h[n], rf[24 + n], y);
      }
      if (l >= lo) atomicAdd(yb + (size_t)s * DI, fmaf(Dv, u, y));
    }
  }
}

// ---------------- LN -> gate -> W_out (two-pass, per-lane, no LDS) ----------
__global__ __launch_bounds__(256) void k_final(const float* __restrict__ y_sum,
    const float* __restrict__ zb, const float* __restrict__ lnw,
    const float* __restrict__ lnb, const float* __restrict__ woT,
    float* __restrict__ out) {
  int blk = blockIdx.x;
  int s2 = blk & 1;
  int tile = blk >> 1;                 // over B*L/64
  int w = __builtin_amdgcn_readfirstlane(threadIdx.x >> 6);
  int lane = threadIdx.x & 63;
  int p = (tile << 6) + lane;          // flattened b*L+s
  int oc0 = s2 * 48 + w * 12;
  const float4* y4 = (const float4*)(y_sum + (size_t)p * DI);
  const float4* z4 = (const float4*)(zb + (size_t)p * DI);
  float s1 = 0.f, ss = 0.f;
  for (int q = 0; q < 48; ++q) {
    float4 v = y4[q];
    s1 += v.x + v.y + v.z + v.w;
    ss += v.x * v.x + v.y * v.y + v.z * v.z + v.w * v.w;
  }
  float mu = s1 * (1.f / DI);
  float var = ss * (1.f / DI) - mu * mu;
  float rs = rsqrtf(var + 1e-5f);
  const float4* lw4 = (const float4*)lnw;
  const float4* lb4 = (const float4*)lnb;
  float acc[12];
  #pragma unroll
  for (int m = 0; m < 12; ++m) acc[m] = 0.f;
  for (int q = 0; q < 48; ++q) {
    float4 yv = y4[q], zv = z4[q], lw = lw4[q], lb = lb4[q];
    float4 g;
    g.x = ((yv.x - mu) * rs * lw.x + lb.x) * (zv.x / (1.f + __expf(-zv.x)));
    g.y = ((yv.y - mu) * rs * lw.y + lb.y) * (zv.y / (1.f + __expf(-zv.y)));
    g.z = ((yv.z - mu) * rs * lw.z + lb.z) * (zv.z / (1.f + __expf(-zv.z)));
    g.w = ((yv.w - mu) * rs * lw.w + lb.w) * (zv.w / (1.f + __expf(-zv.w)));
    const float4* wv = (const float4*)(woT + ((size_t)q * 96 + oc0) * 4);
    #pragma unroll
    for (int m = 0; m < 12; ++m) acc[m] = dot4(g, wv[m], acc[m]);
  }
  float4* o4 = (float4*)(out + (size_t)p * DM + oc0);
  o4[0] = make_float4(acc[0], acc[1], acc[2], acc[3]);
  o4[1] = make_float4(acc[4], acc[5], acc[6], acc[7]);
  o4[2] = make_float4(acc[8], acc[9], acc[10], acc[11]);
}

extern "C" void kernel_launch(void* const* d_in, const int* in_sizes, int n_in,
                              void* d_out, int out_size, void* d_ws, size_t ws_size,
                              hipStream_t stream) {
  const float* x        = (const float*)d_in[0];
  const float* W_in     = (const float*)d_in[1];
  const float* conv_w   = (const float*)d_in[2];
  const float* conv_b   = (const float*)d_in[3];
  const float* x_proj_w = (const float*)d_in[4];
  const float* dt_proj_w= (const float*)d_in[5];
  const float* dt_proj_b= (const float*)d_in[6];
  const float* A_logs   = (const float*)d_in[7];
  const float* Ds       = (const float*)d_in[8];
  const float* ln_w     = (const float*)d_in[9];
  const float* ln_b     = (const float*)d_in[10];
  const float* W_out    = (const float*)d_in[11];
  float* out = (float*)d_out;

  float* ws   = (float*)d_ws;
  float* xe_c = ws;                                     // B*DI*L
  float* zb   = xe_c + (size_t)BATCH * DI * L;
  float* xc_c = zb   + (size_t)BATCH * L * DI;          // conv out; reused as ysum
  float* xc_t = xc_c + (size_t)BATCH * L * DI;
  float* xdbl = xc_t + (size_t)BATCH * L * DI;          // B*K*L*ROWW
  float* wiT  = xdbl + (size_t)BATCH * KDIR * L * ROWW; // 36864
  float* wpT  = wiT + 36864;                            // 46080
  float* woT  = wpT + 46080;                            // 18432
  float* ysum = xc_c;                                   // alias (xc_c dead after k_tr)

  k_wt  <<<396, 256, 0, stream>>>(W_in, x_proj_w, W_out, wiT, wpT, woT);
  k_xz  <<<BATCH * 64 * 8, 256, 0, stream>>>(x, wiT, xe_c, zb);
  k_conv<<<BATCH * DI, 256, 0, stream>>>(xe_c, conv_w, conv_b, xc_c);
  k_tr  <<<BATCH * 6 * 128, 256, 0, stream>>>(xc_c, xc_t);
  hipMemsetAsync(ysum, 0, (size_t)BATCH * L * DI * sizeof(float), stream);
  k_proj<<<BATCH * KDIR * 64, 256, 0, stream>>>(xc_t, wpT, xdbl);
  k_scan<<<BATCH * KDIR * NCHUNK, DI, 0, stream>>>(xc_t, xdbl, dt_proj_w, dt_proj_b,
                                                   A_logs, Ds, ysum);
  k_final<<<BATCH * (L / 64) * 2, 256, 0, stream>>>(ysum, zb, ln_w, ln_b, woT, out);
}